// Round 1
// baseline (406.913 us; speedup 1.0000x reference)
//
#include <hip/hip_runtime.h>
#include <hip/hip_bf16.h>

// Sizes fixed by the reference problem.
#define CN 32
#define RN 256
#define DN 512
#define NN 32
#define LN 256

// LDS layout of main kernel (bytes):
//  sAt   : bf16 [256][264]  = 135168   (attn^T, r-major, +8 pad keeps rows 16B-aligned, breaks bank aliasing)
//  stage : 24576            (phase A: conS 16K + lawsS 8K | phase B: Gs 16K | w12 cross-wave: 4K)
//  w12f  : 1024, nsq : 1024, red : 64
#define SAT_STRIDE 264
#define STAGE_OFF 135168
#define W12F_OFF 159744
#define NSQ_OFF 160768
#define RED_OFF 161792
#define SMEM_TOTAL 161856

typedef short v8s __attribute__((ext_vector_type(8)));
typedef float v4f __attribute__((ext_vector_type(4)));
typedef const __attribute__((address_space(1))) void* gas1_t;
typedef __attribute__((address_space(3))) void* las3_t;

__device__ __forceinline__ void gl2lds16(const void* g, void* l) {
  __builtin_amdgcn_global_load_lds((gas1_t)g, (las3_t)l, 16, 0, 0);
}

__device__ __forceinline__ unsigned short f2bf(float x) {
  unsigned int u = __float_as_uint(x);
  u = (u + 0x7fffu + ((u >> 16) & 1u)) >> 16;  // RNE
  return (unsigned short)u;
}
__device__ __forceinline__ float bf2f(unsigned short h) {
  return __uint_as_float(((unsigned int)h) << 16);
}

// ---------------------------------------------------------------------------
// Prep: fp32 -> bf16 copies of laws & contracts, plus ||contracts[c,r,:]||.
// One block per row (8192 rows of 512 for each tensor).
// ---------------------------------------------------------------------------
__global__ __launch_bounds__(256) void prep_kernel(
    const float* __restrict__ con, const float* __restrict__ laws,
    unsigned short* __restrict__ lawsB, unsigned short* __restrict__ conB,
    float* __restrict__ cnorm) {
  const int b = blockIdx.x;           // row index 0..8191
  const int t = threadIdx.x;
  const int base = b * DN;
  float a0 = laws[base + t], a1 = laws[base + t + 256];
  lawsB[base + t] = f2bf(a0);
  lawsB[base + t + 256] = f2bf(a1);
  float c0 = con[base + t], c1 = con[base + t + 256];
  conB[base + t] = f2bf(c0);
  conB[base + t + 256] = f2bf(c1);
  float s = c0 * c0 + c1 * c1;
#pragma unroll
  for (int m = 1; m < 64; m <<= 1) s += __shfl_xor(s, m, 64);
  __shared__ float r4[4];
  if ((t & 63) == 0) r4[t >> 6] = s;
  __syncthreads();
  if (t == 0) cnorm[b] = sqrtf(r4[0] + r4[1] + r4[2] + r4[3]);
}

// ---------------------------------------------------------------------------
// Gram: G[n][l][l'] = dot(laws[n,l,:], laws[n,l',:]) stored bf16.
// Block = (n, 16-row stripe). Thread t owns column l'=t.
// ---------------------------------------------------------------------------
__global__ __launch_bounds__(256) void gram_kernel(
    const float* __restrict__ laws, unsigned short* __restrict__ G) {
  __shared__ float tile[16 * DN];  // 32 KB, 16 rows fp32
  const int bx = blockIdx.x;
  const int n = bx >> 4;
  const int l0 = (bx & 15) << 4;
  const int t = threadIdx.x;
  const float* base = laws + n * (LN * DN);
  const float4* src = (const float4*)(base + l0 * DN);
  float4* dst = (float4*)tile;
#pragma unroll
  for (int i = 0; i < 8; ++i) dst[t + i * 256] = src[t + i * 256];
  __syncthreads();
  float acc[16];
#pragma unroll
  for (int j = 0; j < 16; ++j) acc[j] = 0.f;
  const float4* row = (const float4*)(base + t * DN);
  for (int q = 0; q < DN / 4; ++q) {
    float4 x = row[q];
#pragma unroll
    for (int j = 0; j < 16; ++j) {
      float4 y = ((const float4*)tile)[j * (DN / 4) + q];  // broadcast
      acc[j] += x.x * y.x + x.y * y.y + x.z * y.z + x.w * y.w;
    }
  }
  unsigned short* g = G + n * (LN * LN);
#pragma unroll
  for (int j = 0; j < 16; ++j) g[(l0 + j) * LN + t] = f2bf(acc[j]);
}

// ---------------------------------------------------------------------------
// Main: one block per (n,c). 256 threads (4 waves).
// Phase A: S = laws[n]@con[c]^T via 16x16x32 bf16 MFMA, softmax rows in-reg,
//          write attn^T (bf16) to LDS, accumulate w12[r] = sum_l a*S_raw.
// Phase B: U = At@G  (G symmetric -> row reads);  nsq[r] = sum_l At[r,l]U[r,l].
// Phase C: sim = sqrt(D)*w12 / (w1*sqrt(nsq)); out[c,n] = log(sum exp(6 sim))/6.
// ---------------------------------------------------------------------------
__global__ __launch_bounds__(256, 1) void main_kernel(
    const int* __restrict__ law_lens, const unsigned short* __restrict__ lawsB,
    const unsigned short* __restrict__ conB, const unsigned short* __restrict__ Gm,
    const float* __restrict__ cnorm, float* __restrict__ out) {
  extern __shared__ char smem[];
  unsigned short* sAt = (unsigned short*)smem;  // [256][264]
  char* stage = smem + STAGE_OFF;
  float* w12f = (float*)(smem + W12F_OFF);
  float* nsq = (float*)(smem + NSQ_OFF);
  float* red = (float*)(smem + RED_OFF);

  const int bid = blockIdx.x;
  const int n = bid >> 5;   // 32 consecutive blocks share one n -> laws/G hot in L2
  const int c = bid & 31;
  const int t = threadIdx.x;
  const int lane = t & 63;
  const int w = t >> 6;
  const int quad = lane >> 4;
  const int l16 = lane & 15;
  const int sub = t & 3;    // staging: which 16B of a 64B LDS row
  const int rQ = t >> 2;    // staging: row within a 64-row group
  const int len = law_lens[n];

  const unsigned short* lawN = lawsB + n * (LN * DN);
  const unsigned short* conC = conB + c * (RN * DN);
  const unsigned short* Gn = Gm + n * (LN * LN);

  unsigned short* conS = (unsigned short*)stage;             // [256][32]
  unsigned short* lawsS = (unsigned short*)(stage + 16384);  // [128][32]

  float w12p[16];
#pragma unroll
  for (int i = 0; i < 16; ++i) w12p[i] = 0.f;

  // ---------------- Phase A ----------------
  for (int pass = 0; pass < 2; ++pass) {
    v4f acc[2][16];
#pragma unroll
    for (int a = 0; a < 2; ++a)
#pragma unroll
      for (int b = 0; b < 16; ++b) acc[a][b] = (v4f){0.f, 0.f, 0.f, 0.f};

    for (int ch = 0; ch < 16; ++ch) {
      const int dk = ch << 5;
      __syncthreads();  // protect staging buffers from previous chunk's readers
#pragma unroll
      for (int i = 0; i < 4; ++i)
        gl2lds16(conC + (i * 64 + rQ) * DN + dk + sub * 8,
                 (char*)conS + i * 4096 + t * 16);
#pragma unroll
      for (int i = 0; i < 2; ++i)
        gl2lds16(lawN + (pass * 128 + i * 64 + rQ) * DN + dk + sub * 8,
                 (char*)lawsS + i * 4096 + t * 16);
      __syncthreads();  // drains vmcnt for global_load_lds
      v8s af0 = *(const v8s*)(lawsS + (w * 32 + l16) * 32 + quad * 8);
      v8s af1 = *(const v8s*)(lawsS + (w * 32 + 16 + l16) * 32 + quad * 8);
#pragma unroll
      for (int rt = 0; rt < 16; ++rt) {
        v8s bf = *(const v8s*)(conS + (rt * 16 + l16) * 32 + quad * 8);
        acc[0][rt] = __builtin_amdgcn_mfma_f32_16x16x32_bf16(af0, bf, acc[0][rt], 0, 0, 0);
        acc[1][rt] = __builtin_amdgcn_mfma_f32_16x16x32_bf16(af1, bf, acc[1][rt], 0, 0, 0);
      }
    }
    // Row ops: each row l lives in 16 lanes of one quad (C layout col=lane&15).
#pragma unroll
    for (int tl = 0; tl < 2; ++tl) {
#pragma unroll
      for (int reg = 0; reg < 4; ++reg) {
        const int lg = pass * 128 + w * 32 + tl * 16 + quad * 4 + reg;
        float v[16], lv[16];
        float ss = 0.f, mx = -1e30f;
#pragma unroll
        for (int rt = 0; rt < 16; ++rt) {
          v[rt] = acc[tl][rt][reg] * 0.04419417382415922f;  // 1/sqrt(512)
          lv[rt] = v[rt] > 0.f ? v[rt] : 0.1f * v[rt];
          ss += lv[rt] * lv[rt];
          mx = fmaxf(mx, lv[rt]);
        }
#pragma unroll
        for (int m = 1; m < 16; m <<= 1) {
          ss += __shfl_xor(ss, m, 64);
          mx = fmaxf(mx, __shfl_xor(mx, m, 64));
        }
        const float inv = 1.f / (sqrtf(ss) + 1e-8f);
        const float xm = mx * inv;
        float e[16];
        float den = 0.f;
#pragma unroll
        for (int rt = 0; rt < 16; ++rt) {
          e[rt] = __expf(lv[rt] * inv - xm);
          den += e[rt];
        }
#pragma unroll
        for (int m = 1; m < 16; m <<= 1) den += __shfl_xor(den, m, 64);
        const float sc = (lg < len) ? 4.f / den : 0.f;  // SMOOTH / denom, masked
#pragma unroll
        for (int rt = 0; rt < 16; ++rt) {
          const float a = e[rt] * sc;
          w12p[rt] += a * v[rt];  // raw (pre-leaky) S -> cosine numerator
          sAt[(rt * 16 + l16) * SAT_STRIDE + lg] = f2bf(a);
        }
      }
    }
  }
  // w12 partials: sum across quads (different l), then across waves via LDS.
#pragma unroll
  for (int rt = 0; rt < 16; ++rt) {
    w12p[rt] += __shfl_xor(w12p[rt], 16, 64);
    w12p[rt] += __shfl_xor(w12p[rt], 32, 64);
  }
  float* w12s = (float*)stage;
  __syncthreads();
  if (lane < 16) {
#pragma unroll
    for (int rt = 0; rt < 16; ++rt) w12s[w * 256 + rt * 16 + lane] = w12p[rt];
  }
  __syncthreads();
  w12f[t] = w12s[t] + w12s[256 + t] + w12s[512 + t] + w12s[768 + t];

  // ---------------- Phase B ----------------
  unsigned short* Gs = (unsigned short*)stage;  // [256][32]
  for (int pass = 0; pass < 2; ++pass) {
    v4f acc[2][16];
#pragma unroll
    for (int a = 0; a < 2; ++a)
#pragma unroll
      for (int b = 0; b < 16; ++b) acc[a][b] = (v4f){0.f, 0.f, 0.f, 0.f};

    for (int ch = 0; ch < 8; ++ch) {
      const int lk = ch << 5;
      __syncthreads();
#pragma unroll
      for (int i = 0; i < 4; ++i)
        gl2lds16(Gn + (i * 64 + rQ) * LN + lk + sub * 8,
                 (char*)Gs + i * 4096 + t * 16);
      __syncthreads();
      v8s af0 = *(const v8s*)(sAt + (pass * 128 + w * 32 + l16) * SAT_STRIDE + lk + quad * 8);
      v8s af1 = *(const v8s*)(sAt + (pass * 128 + w * 32 + 16 + l16) * SAT_STRIDE + lk + quad * 8);
#pragma unroll
      for (int lt = 0; lt < 16; ++lt) {
        v8s bf = *(const v8s*)(Gs + (lt * 16 + l16) * 32 + quad * 8);  // G row l (symmetric)
        acc[0][lt] = __builtin_amdgcn_mfma_f32_16x16x32_bf16(af0, bf, acc[0][lt], 0, 0, 0);
        acc[1][lt] = __builtin_amdgcn_mfma_f32_16x16x32_bf16(af1, bf, acc[1][lt], 0, 0, 0);
      }
    }
    // nsq[r] = sum_l At[r,l] * U[r,l]
#pragma unroll
    for (int tl = 0; tl < 2; ++tl) {
#pragma unroll
      for (int reg = 0; reg < 4; ++reg) {
        const int r = pass * 128 + w * 32 + tl * 16 + quad * 4 + reg;
        float s = 0.f;
#pragma unroll
        for (int lt = 0; lt < 16; ++lt)
          s += acc[tl][lt][reg] * bf2f(sAt[r * SAT_STRIDE + lt * 16 + l16]);
#pragma unroll
        for (int m = 1; m < 16; m <<= 1) s += __shfl_xor(s, m, 64);
        if (l16 == 0) nsq[r] = s;
      }
    }
  }
  __syncthreads();

  // ---------------- Phase C ----------------
  const float w1 = cnorm[c * RN + t];
  const float w2 = sqrtf(fmaxf(nsq[t], 0.f));
  const float sim = (w12f[t] * 22.627416997969522f) / fmaxf(w1 * w2, 1e-8f);
  float p = __expf(6.f * sim);
#pragma unroll
  for (int m = 1; m < 64; m <<= 1) p += __shfl_xor(p, m, 64);
  if (lane == 0) red[w] = p;
  __syncthreads();
  if (t == 0) out[c * NN + n] = logf(red[0] + red[1] + red[2] + red[3]) / 6.f;
}

// ---------------------------------------------------------------------------
extern "C" void kernel_launch(void* const* d_in, const int* in_sizes, int n_in,
                              void* d_out, int out_size, void* d_ws, size_t ws_size,
                              hipStream_t stream) {
  (void)in_sizes; (void)n_in; (void)out_size;
  const float* contracts = (const float*)d_in[0];
  const float* laws = (const float*)d_in[1];
  const int* law_lens = (const int*)d_in[2];
  float* out = (float*)d_out;

  // Workspace layout (21,004,288 B total)
  unsigned short* lawsB = (unsigned short*)d_ws;          // 8 MiB
  unsigned short* conB = lawsB + NN * LN * DN;            // 8 MiB
  unsigned short* G = conB + CN * RN * DN;                // 4 MiB
  float* cnorm = (float*)(G + NN * LN * LN);              // 32 KiB
  if (ws_size < (size_t)21004288) return;  // fail loudly (out stays poisoned)

  hipFuncSetAttribute((const void*)main_kernel,
                      hipFuncAttributeMaxDynamicSharedMemorySize, SMEM_TOTAL);

  prep_kernel<<<8192, 256, 0, stream>>>(contracts, laws, lawsB, conB, cnorm);
  gram_kernel<<<512, 256, 0, stream>>>(laws, G);
  main_kernel<<<1024, 256, SMEM_TOTAL, stream>>>(law_lens, lawsB, conB, G, cnorm, out);
}

// Round 2
// 306.749 us; speedup vs baseline: 1.3265x; 1.3265x over previous
//
#include <hip/hip_runtime.h>
#include <hip/hip_bf16.h>

// Sizes fixed by the reference problem.
#define CN 32
#define RN 256
#define DN 512
#define NN 32
#define LN 256

// LDS layout of main kernel (bytes):
//  sAt   : bf16 [256][256] = 131072, 16B-chunk XOR swizzle (chunk ^= row&7)
//          -> conflict-free row-strided b16 writes, aligned b128 row reads.
//  stage : 32768 (phase A: conS 16K + lawsS 16K | phase B: Gs 16K |
//                 epilogue: w12s 8K + nsqS 1K + red)
//  total : 163840 = exactly 160 KiB (1 block/CU, 8 waves)
#define STAGE_OFF 131072
#define SMEM_TOTAL 163840

typedef short v8s __attribute__((ext_vector_type(8)));
typedef float v4f __attribute__((ext_vector_type(4)));
typedef const __attribute__((address_space(1))) void* gas1_t;
typedef __attribute__((address_space(3))) void* las3_t;

__device__ __forceinline__ void gl2lds16(const void* g, void* l) {
  __builtin_amdgcn_global_load_lds((gas1_t)g, (las3_t)l, 16, 0, 0);
}

__device__ __forceinline__ unsigned short f2bf(float x) {
  unsigned int u = __float_as_uint(x);
  u = (u + 0x7fffu + ((u >> 16) & 1u)) >> 16;  // RNE
  return (unsigned short)u;
}
__device__ __forceinline__ float bf2f(unsigned short h) {
  return __uint_as_float(((unsigned int)h) << 16);
}

// sAt addressing: row-major stride 256 shorts, 16B chunks XOR-swizzled by row.
// bank(write pattern: fixed col, row varies over l16) = 4*((ck^ (r&7))&7)+...
// -> 8 distinct bank groups, 2 lanes each (free).
__device__ __forceinline__ int satIdx(int r, int col) {
  return (r << 8) | ((((col >> 3) ^ (r & 7)) << 3) | (col & 7));
}

// ---------------------------------------------------------------------------
// Prep: fp32 -> bf16 copies of laws & contracts, plus ||contracts[c,r,:]||.
// ---------------------------------------------------------------------------
__global__ __launch_bounds__(256) void prep_kernel(
    const float* __restrict__ con, const float* __restrict__ laws,
    unsigned short* __restrict__ lawsB, unsigned short* __restrict__ conB,
    float* __restrict__ cnorm) {
  const int b = blockIdx.x;  // row index 0..8191
  const int t = threadIdx.x;
  const int base = b * DN;
  float a0 = laws[base + t], a1 = laws[base + t + 256];
  lawsB[base + t] = f2bf(a0);
  lawsB[base + t + 256] = f2bf(a1);
  float c0 = con[base + t], c1 = con[base + t + 256];
  conB[base + t] = f2bf(c0);
  conB[base + t + 256] = f2bf(c1);
  float s = c0 * c0 + c1 * c1;
#pragma unroll
  for (int m = 1; m < 64; m <<= 1) s += __shfl_xor(s, m, 64);
  __shared__ float r4[4];
  if ((t & 63) == 0) r4[t >> 6] = s;
  __syncthreads();
  if (t == 0) cnorm[b] = sqrtf(r4[0] + r4[1] + r4[2] + r4[3]);
}

// ---------------------------------------------------------------------------
// Gram: G[n][l][l'] = dot(laws[n,l,:], laws[n,l',:]) stored bf16.
// ---------------------------------------------------------------------------
__global__ __launch_bounds__(256) void gram_kernel(
    const float* __restrict__ laws, unsigned short* __restrict__ G) {
  __shared__ float tile[16 * DN];  // 32 KB
  const int bx = blockIdx.x;
  const int n = bx >> 4;
  const int l0 = (bx & 15) << 4;
  const int t = threadIdx.x;
  const float* base = laws + n * (LN * DN);
  const float4* src = (const float4*)(base + l0 * DN);
  float4* dst = (float4*)tile;
#pragma unroll
  for (int i = 0; i < 8; ++i) dst[t + i * 256] = src[t + i * 256];
  __syncthreads();
  float acc[16];
#pragma unroll
  for (int j = 0; j < 16; ++j) acc[j] = 0.f;
  const float4* row = (const float4*)(base + t * DN);
  for (int q = 0; q < DN / 4; ++q) {
    float4 x = row[q];
#pragma unroll
    for (int j = 0; j < 16; ++j) {
      float4 y = ((const float4*)tile)[j * (DN / 4) + q];  // broadcast
      acc[j] += x.x * y.x + x.y * y.y + x.z * y.z + x.w * y.w;
    }
  }
  unsigned short* g = G + n * (LN * LN);
#pragma unroll
  for (int j = 0; j < 16; ++j) g[(l0 + j) * LN + t] = f2bf(acc[j]);
}

// ---------------------------------------------------------------------------
// Main: one block per (n,c), 512 threads (8 waves, 2/SIMD for latency hiding).
// Phase A: S = laws[n]@con[c]^T (16x16x32 bf16 MFMA), softmax rows in-reg,
//          attn^T -> sAt (swizzled LDS), w12 partials in registers.
// Phase B: U = At@G; nsq[r] = sum_l At[r,l]*U[r,l].
// Phase C: sim = sqrt(D)*w12/(w1*w2); out[c,n] = LSE_6 over r.
// ---------------------------------------------------------------------------
__global__ __launch_bounds__(512, 2) void main_kernel(
    const int* __restrict__ law_lens, const unsigned short* __restrict__ lawsB,
    const unsigned short* __restrict__ conB, const unsigned short* __restrict__ Gm,
    const float* __restrict__ cnorm, float* __restrict__ out) {
  extern __shared__ char smem[];
  unsigned short* sAt = (unsigned short*)smem;  // [256][256] swizzled
  char* stage = smem + STAGE_OFF;

  const int bid = blockIdx.x;
  const int n = bid >> 5;  // 32 consecutive blocks share one n
  const int c = bid & 31;
  const int t = threadIdx.x;
  const int lane = t & 63;
  const int w = t >> 6;        // wave 0..7
  const int quad = lane >> 4;
  const int l16 = lane & 15;
  const int sub = t & 3;       // staging: which 16B of a 64B row
  const int rQ = t >> 2;       // staging: row 0..127 within a 128-row group
  const int len = law_lens[n];

  const unsigned short* lawN = lawsB + n * (LN * DN);
  const unsigned short* conC = conB + c * (RN * DN);
  const unsigned short* Gn = Gm + n * (LN * LN);

  unsigned short* conS = (unsigned short*)stage;             // [256][32]
  unsigned short* lawsS = (unsigned short*)(stage + 16384);  // [256][32]

  float w12p[16];
#pragma unroll
  for (int i = 0; i < 16; ++i) w12p[i] = 0.f;

  // ---------------- Phase A ----------------
  {
    v4f acc[2][16];
#pragma unroll
    for (int a = 0; a < 2; ++a)
#pragma unroll
      for (int b = 0; b < 16; ++b) acc[a][b] = (v4f){0.f, 0.f, 0.f, 0.f};

    for (int ch = 0; ch < 16; ++ch) {
      const int dk = ch << 5;
      __syncthreads();  // protect staging from previous chunk's readers
#pragma unroll
      for (int i = 0; i < 2; ++i)
        gl2lds16(conC + (i * 128 + rQ) * DN + dk + sub * 8,
                 (char*)conS + i * 8192 + t * 16);
#pragma unroll
      for (int i = 0; i < 2; ++i)
        gl2lds16(lawN + (i * 128 + rQ) * DN + dk + sub * 8,
                 (char*)lawsS + i * 8192 + t * 16);
      __syncthreads();  // drain vmcnt for global_load_lds
      v8s af0 = *(const v8s*)(lawsS + (w * 32 + l16) * 32 + quad * 8);
      v8s af1 = *(const v8s*)(lawsS + (w * 32 + 16 + l16) * 32 + quad * 8);
#pragma unroll
      for (int rt = 0; rt < 16; ++rt) {
        v8s bf = *(const v8s*)(conS + (rt * 16 + l16) * 32 + quad * 8);
        acc[0][rt] = __builtin_amdgcn_mfma_f32_16x16x32_bf16(af0, bf, acc[0][rt], 0, 0, 0);
        acc[1][rt] = __builtin_amdgcn_mfma_f32_16x16x32_bf16(af1, bf, acc[1][rt], 0, 0, 0);
      }
    }
    // Row ops: row l lives in 16 lanes (C layout col=lane&15 -> r index).
#pragma unroll
    for (int tl = 0; tl < 2; ++tl) {
#pragma unroll
      for (int reg = 0; reg < 4; ++reg) {
        const int lg = w * 32 + tl * 16 + quad * 4 + reg;
        float v[16], lv[16];
        float ss = 0.f, mx = -1e30f;
#pragma unroll
        for (int rt = 0; rt < 16; ++rt) {
          v[rt] = acc[tl][rt][reg] * 0.04419417382415922f;  // 1/sqrt(512)
          lv[rt] = v[rt] > 0.f ? v[rt] : 0.1f * v[rt];
          ss += lv[rt] * lv[rt];
          mx = fmaxf(mx, lv[rt]);
        }
#pragma unroll
        for (int m = 1; m < 16; m <<= 1) {
          ss += __shfl_xor(ss, m, 64);
          mx = fmaxf(mx, __shfl_xor(mx, m, 64));
        }
        const float inv = 1.f / (sqrtf(ss) + 1e-8f);
        const float xm = mx * inv;
        float e[16];
        float den = 0.f;
#pragma unroll
        for (int rt = 0; rt < 16; ++rt) {
          e[rt] = __expf(lv[rt] * inv - xm);
          den += e[rt];
        }
#pragma unroll
        for (int m = 1; m < 16; m <<= 1) den += __shfl_xor(den, m, 64);
        const float sc = (lg < len) ? 4.f / den : 0.f;  // SMOOTH/denom, masked
#pragma unroll
        for (int rt = 0; rt < 16; ++rt) {
          const float a = e[rt] * sc;
          w12p[rt] += a * v[rt];  // raw S -> cosine numerator
          sAt[satIdx(rt * 16 + l16, lg)] = f2bf(a);
        }
      }
    }
  }
  // Reduce w12 partials across quads; keep in registers through phase B.
#pragma unroll
  for (int rt = 0; rt < 16; ++rt) {
    w12p[rt] += __shfl_xor(w12p[rt], 16, 64);
    w12p[rt] += __shfl_xor(w12p[rt], 32, 64);
  }

  // ---------------- Phase B ----------------
  unsigned short* Gs = (unsigned short*)stage;  // [256][32]
  float nsv[2][4];
  {
    v4f acc[2][16];
#pragma unroll
    for (int a = 0; a < 2; ++a)
#pragma unroll
      for (int b = 0; b < 16; ++b) acc[a][b] = (v4f){0.f, 0.f, 0.f, 0.f};

    for (int ch = 0; ch < 8; ++ch) {
      const int lk = ch << 5;
      __syncthreads();  // also orders phase-A sAt writes before af reads (ch0)
#pragma unroll
      for (int i = 0; i < 2; ++i)
        gl2lds16(Gn + (i * 128 + rQ) * LN + lk + sub * 8,
                 (char*)Gs + i * 8192 + t * 16);
      __syncthreads();
      v8s af0 = *(const v8s*)(sAt + satIdx(w * 32 + l16, lk + quad * 8));
      v8s af1 = *(const v8s*)(sAt + satIdx(w * 32 + 16 + l16, lk + quad * 8));
#pragma unroll
      for (int lt = 0; lt < 16; ++lt) {
        v8s bf = *(const v8s*)(Gs + (lt * 16 + l16) * 32 + quad * 8);  // G sym
        acc[0][lt] = __builtin_amdgcn_mfma_f32_16x16x32_bf16(af0, bf, acc[0][lt], 0, 0, 0);
        acc[1][lt] = __builtin_amdgcn_mfma_f32_16x16x32_bf16(af1, bf, acc[1][lt], 0, 0, 0);
      }
    }
    // nsq[r] = sum_l At[r,l] * U[r,l] (reads sAt + registers only)
#pragma unroll
    for (int tl = 0; tl < 2; ++tl) {
#pragma unroll
      for (int reg = 0; reg < 4; ++reg) {
        const int r = w * 32 + tl * 16 + quad * 4 + reg;
        float s = 0.f;
#pragma unroll
        for (int lt = 0; lt < 16; ++lt)
          s += acc[tl][lt][reg] * bf2f(sAt[satIdx(r, lt * 16 + l16)]);
#pragma unroll
        for (int m = 1; m < 16; m <<= 1) s += __shfl_xor(s, m, 64);
        nsv[tl][reg] = s;
      }
    }
  }

  // ---------------- Phase C ----------------
  float* w12s = (float*)stage;           // [8][256]
  float* nsqS = (float*)(stage + 8192);  // [256]
  float* red = (float*)(stage + 9216);   // [8]
  __syncthreads();  // all Gs reads done; stage is free for reductions
  if (l16 == 0) {
#pragma unroll
    for (int tl = 0; tl < 2; ++tl)
#pragma unroll
      for (int reg = 0; reg < 4; ++reg)
        nsqS[w * 32 + tl * 16 + quad * 4 + reg] = nsv[tl][reg];
  }
  if (lane < 16) {
#pragma unroll
    for (int rt = 0; rt < 16; ++rt) w12s[w * 256 + rt * 16 + lane] = w12p[rt];
  }
  __syncthreads();
  float p = 0.f;
  if (t < 256) {
    float w12 = 0.f;
#pragma unroll
    for (int i = 0; i < 8; ++i) w12 += w12s[i * 256 + t];
    const float w1 = cnorm[c * RN + t];
    const float w2 = sqrtf(fmaxf(nsqS[t], 0.f));
    const float sim = (w12 * 22.627416997969522f) / fmaxf(w1 * w2, 1e-8f);
    p = __expf(6.f * sim);
  }
#pragma unroll
  for (int m = 1; m < 64; m <<= 1) p += __shfl_xor(p, m, 64);
  __syncthreads();  // reuse of red after w12s reads
  if (lane == 0) red[w] = p;
  __syncthreads();
  if (t == 0) {
    float s = 0.f;
#pragma unroll
    for (int i = 0; i < 8; ++i) s += red[i];
    out[c * NN + n] = logf(s) / 6.f;
  }
}

// ---------------------------------------------------------------------------
extern "C" void kernel_launch(void* const* d_in, const int* in_sizes, int n_in,
                              void* d_out, int out_size, void* d_ws, size_t ws_size,
                              hipStream_t stream) {
  (void)in_sizes; (void)n_in; (void)out_size;
  const float* contracts = (const float*)d_in[0];
  const float* laws = (const float*)d_in[1];
  const int* law_lens = (const int*)d_in[2];
  float* out = (float*)d_out;

  // Workspace layout (21,004,288 B total)
  unsigned short* lawsB = (unsigned short*)d_ws;  // 8 MiB
  unsigned short* conB = lawsB + NN * LN * DN;    // 8 MiB
  unsigned short* G = conB + CN * RN * DN;        // 4 MiB
  float* cnorm = (float*)(G + NN * LN * LN);      // 32 KiB
  if (ws_size < (size_t)21004288) return;

  hipFuncSetAttribute((const void*)main_kernel,
                      hipFuncAttributeMaxDynamicSharedMemorySize, SMEM_TOTAL);

  prep_kernel<<<8192, 256, 0, stream>>>(contracts, laws, lawsB, conB, cnorm);
  gram_kernel<<<512, 256, 0, stream>>>(laws, G);
  main_kernel<<<1024, 512, SMEM_TOTAL, stream>>>(law_lens, lawsB, conB, G, cnorm, out);
}

// Round 3
// 250.288 us; speedup vs baseline: 1.6258x; 1.2256x over previous
//
#include <hip/hip_runtime.h>
#include <hip/hip_bf16.h>

// Sizes fixed by the reference problem.
#define CN 32
#define RN 256
#define DN 512
#define NN 32
#define LN 256

// LDS layout of main kernel (bytes):
//  sAt   : bf16 [256][256] = 131072, 16B-chunk XOR swizzle (chunk ^= r&7)
//  stage : 32768 (A: conS 16K + lawsS 16K | B: Gs 16K | epilogue reductions)
//  total : 163840 = 160 KiB (1 block/CU, 8 waves)
#define STAGE_OFF 131072
#define SMEM_TOTAL 163840

typedef short v8s __attribute__((ext_vector_type(8)));
typedef float v4f __attribute__((ext_vector_type(4)));
typedef const __attribute__((address_space(1))) void* gas1_t;
typedef __attribute__((address_space(3))) void* las3_t;

__device__ __forceinline__ void gl2lds16(const void* g, void* l) {
  __builtin_amdgcn_global_load_lds((gas1_t)g, (las3_t)l, 16, 0, 0);
}

__device__ __forceinline__ unsigned short f2bf(float x) {
  unsigned int u = __float_as_uint(x);
  u = (u + 0x7fffu + ((u >> 16) & 1u)) >> 16;  // RNE
  return (unsigned short)u;
}
__device__ __forceinline__ float bf2f(unsigned short h) {
  return __uint_as_float(((unsigned int)h) << 16);
}

// Staging buffers ([256][32] shorts): 16B chunks XOR-swizzled with (r>>1)&3.
// Writes absorb the swizzle in the global fetch column (gl2lds slot is fixed);
// reads use this helper. Bank proof: bank = 16*(l16&1) + 4*(quad^((l16>>1)&3))
// -> 8 distinct groups over l16=0..7, repeated once -> 2-way (free, m136).
__device__ __forceinline__ const v8s* stgFrag(const unsigned short* buf, int r,
                                              int quad) {
  return (const v8s*)(buf + r * 32 + ((quad ^ ((r >> 1) & 3)) << 3));
}

// sAt addressing: row-major stride 256 shorts, 16B chunks XOR-swizzled by row.
__device__ __forceinline__ int satIdx(int r, int col) {
  return (r << 8) | ((((col >> 3) ^ (r & 7)) << 3) | (col & 7));
}

// ---------------------------------------------------------------------------
// Prep: fp32 -> bf16 copies of laws & contracts, plus ||contracts[c,r,:]||.
// ---------------------------------------------------------------------------
__global__ __launch_bounds__(256) void prep_kernel(
    const float* __restrict__ con, const float* __restrict__ laws,
    unsigned short* __restrict__ lawsB, unsigned short* __restrict__ conB,
    float* __restrict__ cnorm) {
  const int b = blockIdx.x;  // row index 0..8191
  const int t = threadIdx.x;
  const int base = b * DN;
  float a0 = laws[base + t], a1 = laws[base + t + 256];
  lawsB[base + t] = f2bf(a0);
  lawsB[base + t + 256] = f2bf(a1);
  float c0 = con[base + t], c1 = con[base + t + 256];
  conB[base + t] = f2bf(c0);
  conB[base + t + 256] = f2bf(c1);
  float s = c0 * c0 + c1 * c1;
#pragma unroll
  for (int m = 1; m < 64; m <<= 1) s += __shfl_xor(s, m, 64);
  __shared__ float r4[4];
  if ((t & 63) == 0) r4[t >> 6] = s;
  __syncthreads();
  if (t == 0) cnorm[b] = sqrtf(r4[0] + r4[1] + r4[2] + r4[3]);
}

// ---------------------------------------------------------------------------
// Gram via MFMA: G[n] = lawsB[n] @ lawsB[n]^T, bf16 out.
// 128 blocks = (n, 64-row quarter). 8 waves; wave tile 32 rows x 64 cols.
// ---------------------------------------------------------------------------
__global__ __launch_bounds__(512) void gramm_kernel(
    const unsigned short* __restrict__ lawsB, unsigned short* __restrict__ G) {
  __shared__ unsigned short lawsAll[256 * 32];  // 16 KB (B operand: all rows)
  __shared__ unsigned short lawsSub[64 * 32];   // 4 KB  (A operand: 64 rows)
  const int bx = blockIdx.x;
  const int n = bx >> 2;
  const int m0 = (bx & 3) << 6;
  const int t = threadIdx.x;
  const int lane = t & 63;
  const int w = t >> 6;
  const int quad = lane >> 4;
  const int l16 = lane & 15;
  const int sub = t & 3;
  const int rQ = t >> 2;
  const int subx = sub ^ ((rQ >> 1) & 3);  // swizzled source chunk
  const unsigned short* lawN = lawsB + n * (LN * DN);
  const int wr = (w & 1) << 5;   // wave row offset (local in 64)
  const int wc = (w >> 1) << 6;  // wave col offset

  v4f acc[2][4];
#pragma unroll
  for (int a = 0; a < 2; ++a)
#pragma unroll
    for (int b = 0; b < 4; ++b) acc[a][b] = (v4f){0.f, 0.f, 0.f, 0.f};

  for (int ch = 0; ch < 16; ++ch) {
    const int dk = ch << 5;
    __syncthreads();
#pragma unroll
    for (int i = 0; i < 2; ++i)
      gl2lds16(lawN + (i * 128 + rQ) * DN + dk + subx * 8,
               (char*)lawsAll + i * 8192 + t * 16);
    if (t < 256)
      gl2lds16(lawN + (m0 + rQ) * DN + dk + subx * 8, (char*)lawsSub + t * 16);
    __syncthreads();
    v8s af0 = *stgFrag(lawsSub, wr + l16, quad);
    v8s af1 = *stgFrag(lawsSub, wr + 16 + l16, quad);
#pragma unroll
    for (int rt = 0; rt < 4; ++rt) {
      v8s bf = *stgFrag(lawsAll, wc + rt * 16 + l16, quad);
      acc[0][rt] = __builtin_amdgcn_mfma_f32_16x16x32_bf16(af0, bf, acc[0][rt], 0, 0, 0);
      acc[1][rt] = __builtin_amdgcn_mfma_f32_16x16x32_bf16(af1, bf, acc[1][rt], 0, 0, 0);
    }
  }
  unsigned short* g = G + n * (LN * LN);
#pragma unroll
  for (int tl = 0; tl < 2; ++tl)
#pragma unroll
    for (int reg = 0; reg < 4; ++reg) {
      const int l = m0 + wr + tl * 16 + quad * 4 + reg;
#pragma unroll
      for (int rt = 0; rt < 4; ++rt)
        g[l * LN + wc + rt * 16 + l16] = f2bf(acc[tl][rt][reg]);
    }
}

// ---------------------------------------------------------------------------
// Main: one block per (n,c), 512 threads (8 waves).
// Phase A: S = laws[n]@con[c]^T (16x16x32 bf16 MFMA), softmax rows in-reg,
//          attn^T -> sAt (swizzled LDS, b64 packed writes), w12 in registers.
// Phase B: U = At@G; nsq[r] = sum_l At[r,l]*U[r,l].
// Phase C: sim = sqrt(D)*w12/(w1*w2); out[c,n] = LSE_6 over r.
// ---------------------------------------------------------------------------
__global__ __launch_bounds__(512, 2) void main_kernel(
    const int* __restrict__ law_lens, const unsigned short* __restrict__ lawsB,
    const unsigned short* __restrict__ conB, const unsigned short* __restrict__ Gm,
    const float* __restrict__ cnorm, float* __restrict__ out) {
  extern __shared__ char smem[];
  unsigned short* sAt = (unsigned short*)smem;  // [256][256] swizzled
  char* stage = smem + STAGE_OFF;

  const int bid = blockIdx.x;
  const int n = bid >> 5;  // 32 consecutive blocks share one n
  const int c = bid & 31;
  const int t = threadIdx.x;
  const int lane = t & 63;
  const int w = t >> 6;        // wave 0..7
  const int quad = lane >> 4;
  const int l16 = lane & 15;
  const int sub = t & 3;       // staging: which 16B of a 64B row
  const int rQ = t >> 2;       // staging: row 0..127 within group
  const int subx = sub ^ ((rQ >> 1) & 3);  // swizzled source chunk
  const int len = law_lens[n];

  const unsigned short* lawN = lawsB + n * (LN * DN);
  const unsigned short* conC = conB + c * (RN * DN);
  const unsigned short* Gn = Gm + n * (LN * LN);

  unsigned short* conS = (unsigned short*)stage;             // [256][32]
  unsigned short* lawsS = (unsigned short*)(stage + 16384);  // [256][32]

  float w12p[16];
#pragma unroll
  for (int i = 0; i < 16; ++i) w12p[i] = 0.f;

  // ---------------- Phase A ----------------
  {
    v4f acc[2][16];
#pragma unroll
    for (int a = 0; a < 2; ++a)
#pragma unroll
      for (int b = 0; b < 16; ++b) acc[a][b] = (v4f){0.f, 0.f, 0.f, 0.f};

    for (int ch = 0; ch < 16; ++ch) {
      const int dk = ch << 5;
      __syncthreads();  // protect staging from previous chunk's readers
#pragma unroll
      for (int i = 0; i < 2; ++i)
        gl2lds16(conC + (i * 128 + rQ) * DN + dk + subx * 8,
                 (char*)conS + i * 8192 + t * 16);
#pragma unroll
      for (int i = 0; i < 2; ++i)
        gl2lds16(lawN + (i * 128 + rQ) * DN + dk + subx * 8,
                 (char*)lawsS + i * 8192 + t * 16);
      __syncthreads();  // drain vmcnt for global_load_lds
      v8s af0 = *stgFrag(lawsS, w * 32 + l16, quad);
      v8s af1 = *stgFrag(lawsS, w * 32 + 16 + l16, quad);
#pragma unroll
      for (int rt = 0; rt < 16; ++rt) {
        v8s bf = *stgFrag(conS, rt * 16 + l16, quad);
        acc[0][rt] = __builtin_amdgcn_mfma_f32_16x16x32_bf16(af0, bf, acc[0][rt], 0, 0, 0);
        acc[1][rt] = __builtin_amdgcn_mfma_f32_16x16x32_bf16(af1, bf, acc[1][rt], 0, 0, 0);
      }
    }
    // Row ops: row l lives in 16 lanes (C layout col=lane&15 -> r index).
    // The 4 regs of a tile are 4 consecutive columns of sAt -> pack b64 writes.
#pragma unroll
    for (int tl = 0; tl < 2; ++tl) {
      unsigned int pk[16][2];
#pragma unroll
      for (int reg = 0; reg < 4; ++reg) {
        const int lg = w * 32 + tl * 16 + quad * 4 + reg;
        float v[16], lv[16];
        float ss = 0.f, mx = -1e30f;
#pragma unroll
        for (int rt = 0; rt < 16; ++rt) {
          v[rt] = acc[tl][rt][reg] * 0.04419417382415922f;  // 1/sqrt(512)
          lv[rt] = v[rt] > 0.f ? v[rt] : 0.1f * v[rt];
          ss += lv[rt] * lv[rt];
          mx = fmaxf(mx, lv[rt]);
        }
#pragma unroll
        for (int m = 1; m < 16; m <<= 1) {
          ss += __shfl_xor(ss, m, 64);
          mx = fmaxf(mx, __shfl_xor(mx, m, 64));
        }
        const float inv = 1.f / (sqrtf(ss) + 1e-8f);
        const float xm = mx * inv;
        float e[16];
        float den = 0.f;
#pragma unroll
        for (int rt = 0; rt < 16; ++rt) {
          e[rt] = __expf(lv[rt] * inv - xm);
          den += e[rt];
        }
#pragma unroll
        for (int m = 1; m < 16; m <<= 1) den += __shfl_xor(den, m, 64);
        const float sc = (lg < len) ? 4.f / den : 0.f;  // SMOOTH/denom, masked
#pragma unroll
        for (int rt = 0; rt < 16; ++rt) {
          const float a = e[rt] * sc;
          w12p[rt] += a * v[rt];  // raw S -> cosine numerator
          const unsigned int h = f2bf(a);
          if (reg & 1)
            pk[rt][reg >> 1] |= h << 16;
          else
            pk[rt][reg >> 1] = h;
        }
      }
      const int lg0 = w * 32 + tl * 16 + quad * 4;
#pragma unroll
      for (int rt = 0; rt < 16; ++rt)
        *(uint2*)(sAt + satIdx(rt * 16 + l16, lg0)) = *(uint2*)pk[rt];
    }
  }
  // Reduce w12 partials across quads; keep in registers through phase B.
#pragma unroll
  for (int rt = 0; rt < 16; ++rt) {
    w12p[rt] += __shfl_xor(w12p[rt], 16, 64);
    w12p[rt] += __shfl_xor(w12p[rt], 32, 64);
  }

  // ---------------- Phase B ----------------
  unsigned short* Gs = (unsigned short*)stage;  // [256][32]
  float nsv[2][4];
  {
    v4f acc[2][16];
#pragma unroll
    for (int a = 0; a < 2; ++a)
#pragma unroll
      for (int b = 0; b < 16; ++b) acc[a][b] = (v4f){0.f, 0.f, 0.f, 0.f};

    for (int ch = 0; ch < 8; ++ch) {
      const int lk = ch << 5;
      __syncthreads();  // also orders phase-A sAt writes before af reads (ch0)
#pragma unroll
      for (int i = 0; i < 2; ++i)
        gl2lds16(Gn + (i * 128 + rQ) * LN + lk + subx * 8,
                 (char*)Gs + i * 8192 + t * 16);
      __syncthreads();
      v8s af0 = *(const v8s*)(sAt + satIdx(w * 32 + l16, lk + quad * 8));
      v8s af1 = *(const v8s*)(sAt + satIdx(w * 32 + 16 + l16, lk + quad * 8));
#pragma unroll
      for (int lt = 0; lt < 16; ++lt) {
        v8s bf = *stgFrag(Gs, lt * 16 + l16, quad);  // G row l (symmetric)
        acc[0][lt] = __builtin_amdgcn_mfma_f32_16x16x32_bf16(af0, bf, acc[0][lt], 0, 0, 0);
        acc[1][lt] = __builtin_amdgcn_mfma_f32_16x16x32_bf16(af1, bf, acc[1][lt], 0, 0, 0);
      }
    }
    // nsq[r] = sum_l At[r,l] * U[r,l] (reads sAt + registers only)
#pragma unroll
    for (int tl = 0; tl < 2; ++tl) {
#pragma unroll
      for (int reg = 0; reg < 4; ++reg) {
        const int r = w * 32 + tl * 16 + quad * 4 + reg;
        float s = 0.f;
#pragma unroll
        for (int lt = 0; lt < 16; ++lt)
          s += acc[tl][lt][reg] * bf2f(sAt[satIdx(r, lt * 16 + l16)]);
#pragma unroll
        for (int m = 1; m < 16; m <<= 1) s += __shfl_xor(s, m, 64);
        nsv[tl][reg] = s;
      }
    }
  }

  // ---------------- Phase C ----------------
  float* w12s = (float*)stage;           // [8][256]
  float* nsqS = (float*)(stage + 8192);  // [256]
  float* red = (float*)(stage + 9216);   // [8]
  __syncthreads();  // all Gs reads done; stage is free for reductions
  if (l16 == 0) {
#pragma unroll
    for (int tl = 0; tl < 2; ++tl)
#pragma unroll
      for (int reg = 0; reg < 4; ++reg)
        nsqS[w * 32 + tl * 16 + quad * 4 + reg] = nsv[tl][reg];
  }
  if (lane < 16) {
#pragma unroll
    for (int rt = 0; rt < 16; ++rt) w12s[w * 256 + rt * 16 + lane] = w12p[rt];
  }
  __syncthreads();
  float p = 0.f;
  if (t < 256) {
    float w12 = 0.f;
#pragma unroll
    for (int i = 0; i < 8; ++i) w12 += w12s[i * 256 + t];
    const float w1 = cnorm[c * RN + t];
    const float w2 = sqrtf(fmaxf(nsqS[t], 0.f));
    const float sim = (w12 * 22.627416997969522f) / fmaxf(w1 * w2, 1e-8f);
    p = __expf(6.f * sim);
  }
#pragma unroll
  for (int m = 1; m < 64; m <<= 1) p += __shfl_xor(p, m, 64);
  __syncthreads();  // reuse of red after w12s reads
  if (lane == 0) red[w] = p;
  __syncthreads();
  if (t == 0) {
    float s = 0.f;
#pragma unroll
    for (int i = 0; i < 8; ++i) s += red[i];
    out[c * NN + n] = logf(s) / 6.f;
  }
}

// ---------------------------------------------------------------------------
extern "C" void kernel_launch(void* const* d_in, const int* in_sizes, int n_in,
                              void* d_out, int out_size, void* d_ws, size_t ws_size,
                              hipStream_t stream) {
  (void)in_sizes; (void)n_in; (void)out_size;
  const float* contracts = (const float*)d_in[0];
  const float* laws = (const float*)d_in[1];
  const int* law_lens = (const int*)d_in[2];
  float* out = (float*)d_out;

  // Workspace layout (21,004,288 B total)
  unsigned short* lawsB = (unsigned short*)d_ws;  // 8 MiB
  unsigned short* conB = lawsB + NN * LN * DN;    // 8 MiB
  unsigned short* G = conB + CN * RN * DN;        // 4 MiB
  float* cnorm = (float*)(G + NN * LN * LN);      // 32 KiB
  if (ws_size < (size_t)21004288) return;

  hipFuncSetAttribute((const void*)main_kernel,
                      hipFuncAttributeMaxDynamicSharedMemorySize, SMEM_TOTAL);

  prep_kernel<<<8192, 256, 0, stream>>>(contracts, laws, lawsB, conB, cnorm);
  gramm_kernel<<<128, 512, 0, stream>>>(lawsB, G);
  main_kernel<<<1024, 512, SMEM_TOTAL, stream>>>(law_lens, lawsB, conB, G, cnorm, out);
}